// Round 1
// baseline (366.430 us; speedup 1.0000x reference)
//
#include <hip/hip_runtime.h>
#include <math.h>

constexpr int CB   = 8;
constexpr int CN   = 2048;
constexpr int CD   = 8;
constexpr int CDEC = 128;
constexpr int CBN  = CB * CN;
constexpr int NWRD = CN / 64;   // 32 mask words per row
constexpr int JSP  = 8;         // j-split for aggregation parallelism
constexpr int JLEN = CN / JSP;  // 256

// ---------------- prep: h = xW, f1/f2, exps, diag(inv_deg) ----------------
__global__ void prep_k(const float* __restrict__ x, const float* __restrict__ inv_deg,
                       const float* __restrict__ W, const float* __restrict__ a,
                       float4* __restrict__ pk, float4* __restrict__ qk) {
  int t = blockIdx.x * blockDim.x + threadIdx.x;
  if (t >= CBN) return;
  int b = t / CN, n = t - b * CN;
  const float* xr = x + (size_t)t * CD;
  float h[CD];
#pragma unroll
  for (int d = 0; d < CD; ++d) {
    float s = 0.f;
#pragma unroll
    for (int k = 0; k < CD; ++k) s = fmaf(xr[k], W[k * CD + d], s);
    h[d] = s;
  }
  float s1 = 0.f, s2 = 0.f;
#pragma unroll
  for (int d = 0; d < CD; ++d) { s1 = fmaf(h[d], a[d], s1); s2 = fmaf(h[d], a[CD + d], s2); }
  float dv = inv_deg[((size_t)b * CN + n) * CN + n];
  // pk = {f1, E1=exp(f1), F1=exp(0.2 f1), 0}   (mask_k later replaces y,z with g1,g2)
  pk[t] = make_float4(s1, expf(s1), expf(0.2f * s1), 0.f);
  // qk = {f2, E2=exp(f2), F2=exp(0.2 f2), dinv}
  qk[t] = make_float4(s2, expf(s2), expf(0.2f * s2), dv);
}

// ---------------- mask build + softmax row sums (one wave per row j) -------
__global__ void mask_k(const int* __restrict__ adj, float4* __restrict__ pk,
                       const float4* __restrict__ qk, unsigned long long* __restrict__ mask) {
  int gw   = (blockIdx.x * blockDim.x + threadIdx.x) >> 6;  // row index (b*CN+j)
  int lane = threadIdx.x & 63;
  if (gw >= CBN) return;
  int b = gw / CN;
  const int* arow = adj + (size_t)gw * CN;
  float4 pj = pk[gw];
  float f1j = pj.x;
  unsigned long long* mrow = mask + (size_t)gw * NWRD;
  const float4* qb = qk + (size_t)b * CN;
  float A = 0.f, C = 0.f;
  for (int k = 0; k < NWRD; ++k) {
    int i = k * 64 + lane;
    bool bit = arow[i] > 0;
    unsigned long long m = __ballot(bit);
    if (lane == 0) mrow[k] = m;
    float4 q = qb[i];
    bool cond = (f1j + q.x) >= 0.f;
    A += (bit && cond) ? q.y : 0.f;
    C += (bit && !cond) ? q.z : 0.f;
  }
#pragma unroll
  for (int off = 32; off; off >>= 1) { A += __shfl_down(A, off); C += __shfl_down(C, off); }
  if (lane == 0) {
    float s = pj.y * A + pj.z * C;  // E1*sum_pos(E2) + F1*sum_neg(F2)
    float ga = (s > 0.f) ? pj.y / s : 0.f;
    float gb = (s > 0.f) ? pj.z / s : 0.f;
    pk[gw] = make_float4(f1j, ga, gb, 0.f);
  }
}

// ---------------- aggregation: part[js][b,i,d] = sum_{j in chunk} attn[j,i]*feat[j,d]
template <int DIN>
__global__ void agg_k(const float* __restrict__ feat, const unsigned long long* __restrict__ mask,
                      const float4* __restrict__ pk, const float4* __restrict__ qk,
                      float* __restrict__ part) {
  int js = blockIdx.x, ic = blockIdx.y, b = blockIdx.z;
  int tid = threadIdx.x;
  int i  = ic * 256 + tid;
  int gi = b * CN + i;
  float4 q = qk[gi];
  float f2i = q.x, e2i = q.y, ff2i = q.z;
  int wv   = __builtin_amdgcn_readfirstlane(tid >> 6);  // wave index (uniform -> SGPR)
  int lane = tid & 63;
  const unsigned long long* mcol = mask + ((size_t)b * CN + js * JLEN) * NWRD + (ic * 4 + wv);
  const float4* pb = pk + (size_t)b * CN + js * JLEN;
  const float* fb  = feat + ((size_t)b * CN + js * JLEN) * DIN;
  float acc[DIN];
#pragma unroll
  for (int d = 0; d < DIN; ++d) acc[d] = 0.f;
#pragma unroll 4
  for (int jj = 0; jj < JLEN; ++jj) {
    unsigned long long m = mcol[(size_t)jj * NWRD];   // wave-uniform -> s_load
    float4 pj = pb[jj];                               // {f1j, g1j, g2j, _} uniform
    bool cond = (pj.x + f2i) >= 0.f;
    float p = cond ? pj.y * e2i : pj.z * ff2i;
    float w = ((m >> lane) & 1ull) ? p : 0.f;
    const float* fr = fb + jj * DIN;
#pragma unroll
    for (int d = 0; d < DIN; ++d) acc[d] = fmaf(w, fr[d], acc[d]);
  }
  float* pr = part + ((size_t)js * CBN + gi) * DIN;
#pragma unroll
  for (int d = 0; d < DIN; ++d) pr[d] = acc[d];
}

// ---------------- epilogue: combine partials, inv_deg scale, @w, self@b, concat, norm, leaky
template <int DIN>
__global__ void epi_k(const float* __restrict__ part, const float* __restrict__ feat,
                      const float4* __restrict__ qk,
                      const float* __restrict__ wmat, const float* __restrict__ bmat,
                      float* __restrict__ out) {
  int t = blockIdx.x * blockDim.x + threadIdx.x;
  if (t >= CBN) return;
  float ag[DIN];
#pragma unroll
  for (int d = 0; d < DIN; ++d) {
    float s = 0.f;
#pragma unroll
    for (int p_ = 0; p_ < JSP; ++p_) s += part[((size_t)p_ * CBN + t) * DIN + d];
    ag[d] = s;
  }
  float di = qk[t].w;
#pragma unroll
  for (int d = 0; d < DIN; ++d) ag[d] *= di;
  const float* fr = feat + (size_t)t * DIN;
  float c[16];
#pragma unroll
  for (int o = 0; o < 8; ++o) {
    float s1 = 0.f, s2 = 0.f;
#pragma unroll
    for (int d = 0; d < DIN; ++d) {
      s1 = fmaf(ag[d], wmat[d * 8 + o], s1);
      s2 = fmaf(fr[d], bmat[d * 8 + o], s2);
    }
    c[o] = s1;
    c[8 + o] = s2;
  }
  float nn = 0.f;
#pragma unroll
  for (int k = 0; k < 16; ++k) nn += c[k] * c[k];
  float inv = 1.f / fmaxf(sqrtf(nn), 1e-12f);
  float* orow = out + (size_t)t * 16;
#pragma unroll
  for (int k = 0; k < 16; ++k) {
    float v = c[k] * inv;
    orow[k] = (v >= 0.f) ? v : 0.1f * v;  // outer leaky 0.1
  }
}

// ---------------- decoder: ypred[b] = (da P1) P2 (db P1)^T ----------------
__global__ void dec_k(const float* __restrict__ out3, const float* __restrict__ P1,
                      const float* __restrict__ P2, float* __restrict__ y) {
  int b = blockIdx.x;
  int t = threadIdx.x;  // 128 threads
  __shared__ float vsh[CDEC];
  __shared__ float red[CDEC];
  const float* da = out3 + ((size_t)b * CN + (CN - 2)) * 16;
  const float* db = out3 + ((size_t)b * CN + (CN - 1)) * 16;
  float ue = 0.f, ve = 0.f;
#pragma unroll
  for (int i = 0; i < 16; ++i) {
    ue = fmaf(da[i], P1[i * CDEC + t], ue);
    ve = fmaf(db[i], P1[i * CDEC + t], ve);
  }
  vsh[t] = ve;
  __syncthreads();
  float s = 0.f;
  for (int e2 = 0; e2 < CDEC; ++e2) s = fmaf(P2[t * CDEC + e2], vsh[e2], s);
  s *= ue;
  red[t] = s;
  __syncthreads();
  for (int off = 64; off; off >>= 1) {
    if (t < off) red[t] += red[t + off];
    __syncthreads();
  }
  if (t == 0) y[b] = red[0];
}

extern "C" void kernel_launch(void* const* d_in, const int* in_sizes, int n_in,
                              void* d_out, int out_size, void* d_ws, size_t ws_size,
                              hipStream_t stream) {
  const float* x       = (const float*)d_in[0];
  const int*   adj     = (const int*)d_in[1];
  const float* inv_deg = (const float*)d_in[2];
  const float* W       = (const float*)d_in[3];
  const float* a       = (const float*)d_in[4];
  const float* w1      = (const float*)d_in[5];
  const float* b1      = (const float*)d_in[6];
  const float* w2      = (const float*)d_in[7];
  const float* b2      = (const float*)d_in[8];
  const float* w3      = (const float*)d_in[9];
  const float* b3      = (const float*)d_in[10];
  const float* P1      = (const float*)d_in[11];
  const float* P2      = (const float*)d_in[12];
  float* y = (float*)d_out;

  char* base = (char*)d_ws;
  size_t off = 0;
  auto alloc = [&](size_t bytes) -> void* {
    void* r = base + off;
    off += (bytes + 255) & ~(size_t)255;
    return r;
  };
  float4* pk = (float4*)alloc(sizeof(float4) * CBN);
  float4* qk = (float4*)alloc(sizeof(float4) * CBN);
  unsigned long long* mask = (unsigned long long*)alloc(sizeof(unsigned long long) * (size_t)CBN * NWRD);
  float* out1 = (float*)alloc(sizeof(float) * (size_t)CBN * 16);
  float* out2 = (float*)alloc(sizeof(float) * (size_t)CBN * 16);
  float* out3 = (float*)alloc(sizeof(float) * (size_t)CBN * 16);
  float* part = (float*)alloc(sizeof(float) * (size_t)JSP * CBN * 16);

  hipLaunchKernelGGL(prep_k, dim3(CBN / 256), dim3(256), 0, stream, x, inv_deg, W, a, pk, qk);
  hipLaunchKernelGGL(mask_k, dim3(CBN / 4), dim3(256), 0, stream, adj, pk, qk, mask);

  // layer 1 (feat = x, DIN=8)
  hipLaunchKernelGGL(agg_k<8>, dim3(JSP, CN / 256, CB), dim3(256), 0, stream, x, mask, pk, qk, part);
  hipLaunchKernelGGL(epi_k<8>, dim3(CBN / 256), dim3(256), 0, stream, part, x, qk, w1, b1, out1);
  // layer 2 (feat = out1, DIN=16)
  hipLaunchKernelGGL(agg_k<16>, dim3(JSP, CN / 256, CB), dim3(256), 0, stream, out1, mask, pk, qk, part);
  hipLaunchKernelGGL(epi_k<16>, dim3(CBN / 256), dim3(256), 0, stream, part, out1, qk, w2, b2, out2);
  // layer 3 (feat = out2, DIN=16)
  hipLaunchKernelGGL(agg_k<16>, dim3(JSP, CN / 256, CB), dim3(256), 0, stream, out2, mask, pk, qk, part);
  hipLaunchKernelGGL(epi_k<16>, dim3(CBN / 256), dim3(256), 0, stream, part, out2, qk, w3, b3, out3);

  hipLaunchKernelGGL(dec_k, dim3(CB), dim3(CDEC), 0, stream, out3, P1, P2, y);
}

// Round 3
// 148.288 us; speedup vs baseline: 2.4711x; 2.4711x over previous
//
#include <hip/hip_runtime.h>
#include <math.h>

constexpr int CB   = 8;
constexpr int CN   = 2048;
constexpr int CD   = 8;
constexpr int CDEC = 128;
constexpr int CBN  = CB * CN;
constexpr int NWRD = CN / 64;   // 32 mask words per row
constexpr int JSP  = 32;        // j-split for aggregation parallelism
constexpr int JLEN = CN / JSP;  // 64

// ---------------- prep: h = xW, f1/f2, exps, diag(inv_deg) ----------------
__global__ void prep_k(const float* __restrict__ x, const float* __restrict__ inv_deg,
                       const float* __restrict__ W, const float* __restrict__ a,
                       float4* __restrict__ pk, float4* __restrict__ qk) {
  int t = blockIdx.x * blockDim.x + threadIdx.x;
  if (t >= CBN) return;
  int b = t / CN, n = t - b * CN;
  const float* xr = x + (size_t)t * CD;
  float h[CD];
#pragma unroll
  for (int d = 0; d < CD; ++d) {
    float s = 0.f;
#pragma unroll
    for (int k = 0; k < CD; ++k) s = fmaf(xr[k], W[k * CD + d], s);
    h[d] = s;
  }
  float s1 = 0.f, s2 = 0.f;
#pragma unroll
  for (int d = 0; d < CD; ++d) { s1 = fmaf(h[d], a[d], s1); s2 = fmaf(h[d], a[CD + d], s2); }
  float dv = inv_deg[((size_t)b * CN + n) * CN + n];
  // pk = {f1, E1=exp(f1), F1=exp(0.2 f1), 0}   (mask_k replaces y,z with g1,g2)
  pk[t] = make_float4(s1, expf(s1), expf(0.2f * s1), 0.f);
  // qk = {f2, E2=exp(f2), F2=exp(0.2 f2), dinv}
  qk[t] = make_float4(s2, expf(s2), expf(0.2f * s2), dv);
}

// ------- mask build (transposed layout) + softmax row sums (1 wave/row j) --
__global__ void mask_k(const int* __restrict__ adj, float4* __restrict__ pk,
                       const float4* __restrict__ qk, unsigned long long* __restrict__ maskT) {
  int gw   = (blockIdx.x * blockDim.x + threadIdx.x) >> 6;  // row index (b*CN+j)
  int lane = threadIdx.x & 63;
  if (gw >= CBN) return;
  int b = gw / CN, j = gw - b * CN;
  const int* arow = adj + (size_t)gw * CN;
  float4 pj = pk[gw];
  float f1j = pj.x;
  const float4* qb = qk + (size_t)b * CN;
  float A = 0.f, C = 0.f;
  for (int k = 0; k < NWRD; ++k) {
    int i = k * 64 + lane;
    bool bit = arow[i] > 0;
    unsigned long long m = __ballot(bit);
    if (lane == 0) maskT[((size_t)(b * NWRD + k)) * CN + j] = m;  // [b][word][j]
    float4 q = qb[i];
    bool cond = (f1j + q.x) >= 0.f;
    A += (bit && cond) ? q.y : 0.f;
    C += (bit && !cond) ? q.z : 0.f;
  }
#pragma unroll
  for (int off = 32; off; off >>= 1) { A += __shfl_down(A, off); C += __shfl_down(C, off); }
  if (lane == 0) {
    float s = pj.y * A + pj.z * C;  // E1*sum_pos(E2) + F1*sum_neg(F2)
    float ga = (s > 0.f) ? pj.y / s : 0.f;
    float gb = (s > 0.f) ? pj.z / s : 0.f;
    pk[gw] = make_float4(f1j, ga, gb, 0.f);
  }
}

// --- aggregation: part[js][b,i][o] = (sum_{j in chunk} attn[j,i]*feat[j,:]) @ wmat
// each thread owns two i columns (i, i+256); per-j data is wave-uniform -> s_loads
template <int DIN>
__global__ __launch_bounds__(256) void agg_k(const float* __restrict__ feat,
                      const unsigned long long* __restrict__ maskT,
                      const float4* __restrict__ pk, const float4* __restrict__ qk,
                      const float* __restrict__ wmat, float* __restrict__ part) {
  const int js = blockIdx.x, ic = blockIdx.y, b = blockIdx.z;
  const int t = threadIdx.x;
  const int w = t >> 6, lane = t & 63;
  const int i1 = ic * 512 + t;   // slot 0
  const int i2 = i1 + 256;       // slot 1
  const int gi1 = b * CN + i1, gi2 = b * CN + i2;
  float4 q1 = qk[gi1], q2 = qk[gi2];
  const unsigned long long* mc1 = maskT + ((size_t)(b * NWRD + ic * 8 + w)) * CN + js * JLEN;
  const unsigned long long* mc2 = maskT + ((size_t)(b * NWRD + ic * 8 + 4 + w)) * CN + js * JLEN;
  const float4* pb = pk + (size_t)b * CN + js * JLEN;
  const float* fb  = feat + ((size_t)b * CN + js * JLEN) * DIN;
  float acc1[DIN], acc2[DIN];
#pragma unroll
  for (int d = 0; d < DIN; ++d) { acc1[d] = 0.f; acc2[d] = 0.f; }
#pragma unroll 4
  for (int jj = 0; jj < JLEN; ++jj) {
    unsigned long long m1 = mc1[jj];            // wave-uniform, contiguous stream
    unsigned long long m2 = mc2[jj];
    float4 pj = pb[jj];                         // {f1j, g1j, g2j, _} uniform
    const float* fr = fb + jj * DIN;            // uniform
    bool c1 = (pj.x + q1.x) >= 0.f;
    float wA = c1 ? pj.y * q1.y : pj.z * q1.z;
    wA = ((m1 >> lane) & 1ull) ? wA : 0.f;
    bool c2 = (pj.x + q2.x) >= 0.f;
    float wB = c2 ? pj.y * q2.y : pj.z * q2.z;
    wB = ((m2 >> lane) & 1ull) ? wB : 0.f;
#pragma unroll
    for (int d = 0; d < DIN; ++d) {
      acc1[d] = fmaf(wA, fr[d], acc1[d]);
      acc2[d] = fmaf(wB, fr[d], acc2[d]);
    }
  }
  // fold the @wmat (DIN -> 8) into the partial store
  float* p1 = part + ((size_t)js * CBN + gi1) * 8;
  float* p2 = part + ((size_t)js * CBN + gi2) * 8;
#pragma unroll
  for (int o = 0; o < 8; ++o) {
    float s1 = 0.f, s2 = 0.f;
#pragma unroll
    for (int d = 0; d < DIN; ++d) {
      s1 = fmaf(acc1[d], wmat[d * 8 + o], s1);
      s2 = fmaf(acc2[d], wmat[d * 8 + o], s2);
    }
    p1[o] = s1;
    p2[o] = s2;
  }
}

// ---- epilogue: sum partials, inv_deg scale, self@b, concat, norm, leaky ----
template <int DIN>
__global__ void epi_k(const float* __restrict__ part, const float* __restrict__ feat,
                      const float4* __restrict__ qk, const float* __restrict__ bmat,
                      float* __restrict__ out) {
  int t = blockIdx.x * blockDim.x + threadIdx.x;
  if (t >= CBN) return;
  float ag[8];
#pragma unroll
  for (int o = 0; o < 8; ++o) ag[o] = 0.f;
  for (int p_ = 0; p_ < JSP; ++p_) {
    const float* pr = part + ((size_t)p_ * CBN + t) * 8;
#pragma unroll
    for (int o = 0; o < 8; ++o) ag[o] += pr[o];
  }
  float di = qk[t].w;
  const float* fr = feat + (size_t)t * DIN;
  float c[16];
#pragma unroll
  for (int o = 0; o < 8; ++o) {
    float s2 = 0.f;
#pragma unroll
    for (int d = 0; d < DIN; ++d) s2 = fmaf(fr[d], bmat[d * 8 + o], s2);
    c[o] = ag[o] * di;
    c[8 + o] = s2;
  }
  float nn = 0.f;
#pragma unroll
  for (int k = 0; k < 16; ++k) nn += c[k] * c[k];
  float inv = 1.f / fmaxf(sqrtf(nn), 1e-12f);
  float* orow = out + (size_t)t * 16;
#pragma unroll
  for (int k = 0; k < 16; ++k) {
    float v = c[k] * inv;
    orow[k] = (v >= 0.f) ? v : 0.1f * v;  // outer leaky 0.1
  }
}

// ---------------- decoder: ypred[b] = (da P1) P2 (db P1)^T ----------------
__global__ void dec_k(const float* __restrict__ out3, const float* __restrict__ P1,
                      const float* __restrict__ P2, float* __restrict__ y) {
  int b = blockIdx.x;
  int t = threadIdx.x;  // 128 threads
  __shared__ float vsh[CDEC];
  __shared__ float red[CDEC];
  const float* da = out3 + ((size_t)b * CN + (CN - 2)) * 16;
  const float* db = out3 + ((size_t)b * CN + (CN - 1)) * 16;
  float ue = 0.f, ve = 0.f;
#pragma unroll
  for (int i = 0; i < 16; ++i) {
    ue = fmaf(da[i], P1[i * CDEC + t], ue);
    ve = fmaf(db[i], P1[i * CDEC + t], ve);
  }
  vsh[t] = ve;
  __syncthreads();
  float s = 0.f;
  for (int e2 = 0; e2 < CDEC; ++e2) s = fmaf(P2[t * CDEC + e2], vsh[e2], s);
  s *= ue;
  red[t] = s;
  __syncthreads();
  for (int off = 64; off; off >>= 1) {
    if (t < off) red[t] += red[t + off];
    __syncthreads();
  }
  if (t == 0) y[b] = red[0];
}

extern "C" void kernel_launch(void* const* d_in, const int* in_sizes, int n_in,
                              void* d_out, int out_size, void* d_ws, size_t ws_size,
                              hipStream_t stream) {
  const float* x       = (const float*)d_in[0];
  const int*   adj     = (const int*)d_in[1];
  const float* inv_deg = (const float*)d_in[2];
  const float* W       = (const float*)d_in[3];
  const float* a       = (const float*)d_in[4];
  const float* w1      = (const float*)d_in[5];
  const float* b1      = (const float*)d_in[6];
  const float* w2      = (const float*)d_in[7];
  const float* b2      = (const float*)d_in[8];
  const float* w3      = (const float*)d_in[9];
  const float* b3      = (const float*)d_in[10];
  const float* P1      = (const float*)d_in[11];
  const float* P2      = (const float*)d_in[12];
  float* y = (float*)d_out;

  char* base = (char*)d_ws;
  size_t off = 0;
  auto alloc = [&](size_t bytes) -> void* {
    void* r = base + off;
    off += (bytes + 255) & ~(size_t)255;
    return r;
  };
  float4* pk = (float4*)alloc(sizeof(float4) * CBN);
  float4* qk = (float4*)alloc(sizeof(float4) * CBN);
  unsigned long long* maskT = (unsigned long long*)alloc(sizeof(unsigned long long) * (size_t)CBN * NWRD);
  float* out1 = (float*)alloc(sizeof(float) * (size_t)CBN * 16);
  float* out2 = (float*)alloc(sizeof(float) * (size_t)CBN * 16);
  float* out3 = (float*)alloc(sizeof(float) * (size_t)CBN * 16);
  float* part = (float*)alloc(sizeof(float) * (size_t)JSP * CBN * 8);

  hipLaunchKernelGGL(prep_k, dim3(CBN / 256), dim3(256), 0, stream, x, inv_deg, W, a, pk, qk);
  hipLaunchKernelGGL(mask_k, dim3(CBN / 4), dim3(256), 0, stream, adj, pk, qk, maskT);

  // layer 1 (feat = x, DIN=8)
  hipLaunchKernelGGL(agg_k<8>, dim3(JSP, 4, CB), dim3(256), 0, stream, x, maskT, pk, qk, w1, part);
  hipLaunchKernelGGL(epi_k<8>, dim3(CBN / 256), dim3(256), 0, stream, part, x, qk, b1, out1);
  // layer 2 (feat = out1, DIN=16)
  hipLaunchKernelGGL(agg_k<16>, dim3(JSP, 4, CB), dim3(256), 0, stream, out1, maskT, pk, qk, w2, part);
  hipLaunchKernelGGL(epi_k<16>, dim3(CBN / 256), dim3(256), 0, stream, part, out1, qk, b2, out2);
  // layer 3 (feat = out2, DIN=16)
  hipLaunchKernelGGL(agg_k<16>, dim3(JSP, 4, CB), dim3(256), 0, stream, out2, maskT, pk, qk, w3, part);
  hipLaunchKernelGGL(epi_k<16>, dim3(CBN / 256), dim3(256), 0, stream, part, out2, qk, b3, out3);

  hipLaunchKernelGGL(dec_k, dim3(CB), dim3(CDEC), 0, stream, out3, P1, P2, y);
}

// Round 4
// 125.589 us; speedup vs baseline: 2.9177x; 1.1807x over previous
//
#include <hip/hip_runtime.h>
#include <math.h>

constexpr int CB   = 8;
constexpr int CN   = 2048;
constexpr int CD   = 8;
constexpr int CDEC = 128;
constexpr int CBN  = CB * CN;
constexpr int NWRD = CN / 64;   // 32 mask words per row
constexpr int JSP  = 64;        // j-split for aggregation parallelism
constexpr int JLEN = CN / JSP;  // 32

// lane-select: r = mask-bit[lane] ? p : 0  (mask is wave-uniform -> SGPR pair)
__device__ inline float msel(unsigned long long m, float p) {
  float r;
  asm("v_cndmask_b32 %0, 0, %1, %2" : "=v"(r) : "v"(p), "s"(m));
  return r;
}

// ---------------- prep: h = xW, f1/f2, exps, diag(inv_deg) ----------------
__global__ void prep_k(const float* __restrict__ x, const float* __restrict__ inv_deg,
                       const float* __restrict__ W, const float* __restrict__ a,
                       float4* __restrict__ pk, float4* __restrict__ qk) {
  int t = blockIdx.x * blockDim.x + threadIdx.x;
  if (t >= CBN) return;
  int b = t / CN, n = t - b * CN;
  const float* xr = x + (size_t)t * CD;
  float h[CD];
#pragma unroll
  for (int d = 0; d < CD; ++d) {
    float s = 0.f;
#pragma unroll
    for (int k = 0; k < CD; ++k) s = fmaf(xr[k], W[k * CD + d], s);
    h[d] = s;
  }
  float s1 = 0.f, s2 = 0.f;
#pragma unroll
  for (int d = 0; d < CD; ++d) { s1 = fmaf(h[d], a[d], s1); s2 = fmaf(h[d], a[CD + d], s2); }
  float dv = inv_deg[((size_t)b * CN + n) * CN + n];
  pk[t] = make_float4(s1, expf(s1), expf(0.2f * s1), 0.f);
  qk[t] = make_float4(s2, expf(s2), expf(0.2f * s2), dv);
}

// ------- mask build (transposed layout) + softmax row sums (1 wave/row j) --
__global__ void mask_k(const int* __restrict__ adj, float4* __restrict__ pk,
                       const float4* __restrict__ qk, unsigned long long* __restrict__ maskT) {
  int gw   = (blockIdx.x * blockDim.x + threadIdx.x) >> 6;  // row index (b*CN+j)
  int lane = threadIdx.x & 63;
  if (gw >= CBN) return;
  int b = gw / CN, j = gw - b * CN;
  const int* arow = adj + (size_t)gw * CN;
  float4 pj = pk[gw];
  float f1j = pj.x;
  const float4* qb = qk + (size_t)b * CN;
  float A = 0.f, C = 0.f;
  for (int k = 0; k < NWRD; ++k) {
    int i = k * 64 + lane;
    bool bit = arow[i] > 0;
    unsigned long long m = __ballot(bit);
    if (lane == 0) maskT[((size_t)(b * NWRD + k)) * CN + j] = m;  // [b][word][j]
    float4 q = qb[i];
    bool cond = (f1j + q.x) >= 0.f;
    A += (bit && cond) ? q.y : 0.f;
    C += (bit && !cond) ? q.z : 0.f;
  }
#pragma unroll
  for (int off = 32; off; off >>= 1) { A += __shfl_down(A, off); C += __shfl_down(C, off); }
  if (lane == 0) {
    float s = pj.y * A + pj.z * C;  // E1*sum_pos(E2) + F1*sum_neg(F2)
    float ga = (s > 0.f) ? pj.y / s : 0.f;
    float gb = (s > 0.f) ? pj.z / s : 0.f;
    pk[gw] = make_float4(f1j, ga, gb, 0.f);
  }
}

// --- aggregation: part[js][b,i][o] = (sum_{j in chunk} attn[j,i]*feat[j,:]) @ wmat
// attn[j,i] = max(g1j*E2i, g2j*F2i) masked   (exp∘leaky = max of branch exps)
template <int DIN>
__global__ __launch_bounds__(256) void agg_k(const float* __restrict__ feat,
                      const unsigned long long* __restrict__ maskT,
                      const float4* __restrict__ pk, const float4* __restrict__ qk,
                      const float* __restrict__ wmat, float* __restrict__ part) {
  const int js = blockIdx.x, ic = blockIdx.y, b = blockIdx.z;
  const int t = threadIdx.x;
  const int w = __builtin_amdgcn_readfirstlane(t >> 6);
  const int i1 = ic * 512 + t;   // slot 0
  const int i2 = i1 + 256;       // slot 1
  const int gi1 = b * CN + i1, gi2 = b * CN + i2;
  float4 q1 = qk[gi1], q2 = qk[gi2];
  const unsigned long long* mc1 = maskT + ((size_t)(b * NWRD + ic * 8 + w)) * CN + js * JLEN;
  const unsigned long long* mc2 = maskT + ((size_t)(b * NWRD + ic * 8 + 4 + w)) * CN + js * JLEN;
  const float4* pb = pk + (size_t)b * CN + js * JLEN;
  const float* fb  = feat + ((size_t)b * CN + js * JLEN) * DIN;
  float acc1[DIN], acc2[DIN];
#pragma unroll
  for (int d = 0; d < DIN; ++d) { acc1[d] = 0.f; acc2[d] = 0.f; }
#pragma unroll 4
  for (int jj = 0; jj < JLEN; ++jj) {
    unsigned long long m1 = mc1[jj];            // wave-uniform, contiguous stream
    unsigned long long m2 = mc2[jj];
    float4 pj = pb[jj];                         // {f1j, g1j, g2j, _} uniform
    const float* fr = fb + jj * DIN;            // uniform
    float wA = msel(m1, fmaxf(pj.y * q1.y, pj.z * q1.z));
    float wB = msel(m2, fmaxf(pj.y * q2.y, pj.z * q2.z));
#pragma unroll
    for (int d = 0; d < DIN; ++d) {
      acc1[d] = fmaf(wA, fr[d], acc1[d]);
      acc2[d] = fmaf(wB, fr[d], acc2[d]);
    }
  }
  // fold the @wmat (DIN -> 8) into the partial store
  float o1[8], o2[8];
#pragma unroll
  for (int o = 0; o < 8; ++o) {
    float s1 = 0.f, s2 = 0.f;
#pragma unroll
    for (int d = 0; d < DIN; ++d) {
      s1 = fmaf(acc1[d], wmat[d * 8 + o], s1);
      s2 = fmaf(acc2[d], wmat[d * 8 + o], s2);
    }
    o1[o] = s1;
    o2[o] = s2;
  }
  float4* p1 = (float4*)(part + ((size_t)js * CBN + gi1) * 8);
  float4* p2 = (float4*)(part + ((size_t)js * CBN + gi2) * 8);
  p1[0] = make_float4(o1[0], o1[1], o1[2], o1[3]);
  p1[1] = make_float4(o1[4], o1[5], o1[6], o1[7]);
  p2[0] = make_float4(o2[0], o2[1], o2[2], o2[3]);
  p2[1] = make_float4(o2[4], o2[5], o2[6], o2[7]);
}

// ---- epilogue: sum partials, inv_deg scale, self@b, concat, norm, leaky ----
template <int DIN>
__global__ void epi_k(const float* __restrict__ part, const float* __restrict__ feat,
                      const float4* __restrict__ qk, const float* __restrict__ bmat,
                      float* __restrict__ out) {
  int t = blockIdx.x * blockDim.x + threadIdx.x;
  if (t >= CBN) return;
  float4 a0 = make_float4(0.f, 0.f, 0.f, 0.f), a1 = a0;
  for (int p_ = 0; p_ < JSP; ++p_) {
    const float4* pr = (const float4*)(part + ((size_t)p_ * CBN + t) * 8);
    float4 r0 = pr[0], r1 = pr[1];
    a0.x += r0.x; a0.y += r0.y; a0.z += r0.z; a0.w += r0.w;
    a1.x += r1.x; a1.y += r1.y; a1.z += r1.z; a1.w += r1.w;
  }
  float ag[8] = {a0.x, a0.y, a0.z, a0.w, a1.x, a1.y, a1.z, a1.w};
  float di = qk[t].w;
  const float* fr = feat + (size_t)t * DIN;
  float c[16];
#pragma unroll
  for (int o = 0; o < 8; ++o) {
    float s2 = 0.f;
#pragma unroll
    for (int d = 0; d < DIN; ++d) s2 = fmaf(fr[d], bmat[d * 8 + o], s2);
    c[o] = ag[o] * di;
    c[8 + o] = s2;
  }
  float nn = 0.f;
#pragma unroll
  for (int k = 0; k < 16; ++k) nn += c[k] * c[k];
  float inv = 1.f / fmaxf(sqrtf(nn), 1e-12f);
  float4* orow = (float4*)(out + (size_t)t * 16);
#pragma unroll
  for (int q = 0; q < 4; ++q) {
    float v0 = c[q*4+0]*inv, v1 = c[q*4+1]*inv, v2 = c[q*4+2]*inv, v3 = c[q*4+3]*inv;
    orow[q] = make_float4(v0 >= 0.f ? v0 : 0.1f*v0, v1 >= 0.f ? v1 : 0.1f*v1,
                          v2 >= 0.f ? v2 : 0.1f*v2, v3 >= 0.f ? v3 : 0.1f*v3);
  }
}

// ---- fused layer 3 + decoder: only rows i = N-2, N-1 are ever consumed ----
__global__ __launch_bounds__(1024) void fused3_k(
    const float* __restrict__ out2, const unsigned long long* __restrict__ maskT,
    const float4* __restrict__ pk, const float4* __restrict__ qk,
    const float* __restrict__ w3, const float* __restrict__ b3,
    const float* __restrict__ P1, const float* __restrict__ P2,
    float* __restrict__ y) {
  const int b = blockIdx.x;
  const int t = threadIdx.x;
  const int lane = t & 63, wv = t >> 6;  // 16 waves
  const int ia = CN - 2, ib = CN - 1;
  float4 qa = qk[b * CN + ia], qb = qk[b * CN + ib];
  float accA[16], accB[16];
#pragma unroll
  for (int d = 0; d < 16; ++d) { accA[d] = 0.f; accB[d] = 0.f; }
  const unsigned long long* mrow = maskT + ((size_t)(b * NWRD + (NWRD - 1))) * CN;
  for (int j = t; j < CN; j += 1024) {
    unsigned long long m = mrow[j];
    float4 pj = pk[b * CN + j];
    const float4* fr = (const float4*)(out2 + ((size_t)(b * CN + j)) * 16);
    float wA = fmaxf(pj.y * qa.y, pj.z * qa.z);
    wA = ((m >> 62) & 1ull) ? wA : 0.f;     // bit for i = N-2
    float wB = fmaxf(pj.y * qb.y, pj.z * qb.z);
    wB = (m >> 63) ? wB : 0.f;              // bit for i = N-1
    float4 f0 = fr[0], f1 = fr[1], f2 = fr[2], f3 = fr[3];
    float ff[16] = {f0.x,f0.y,f0.z,f0.w, f1.x,f1.y,f1.z,f1.w,
                    f2.x,f2.y,f2.z,f2.w, f3.x,f3.y,f3.z,f3.w};
#pragma unroll
    for (int d = 0; d < 16; ++d) {
      accA[d] = fmaf(wA, ff[d], accA[d]);
      accB[d] = fmaf(wB, ff[d], accB[d]);
    }
  }
#pragma unroll
  for (int d = 0; d < 16; ++d) {
#pragma unroll
    for (int off = 32; off; off >>= 1) {
      accA[d] += __shfl_down(accA[d], off);
      accB[d] += __shfl_down(accB[d], off);
    }
  }
  __shared__ float redA[16][16], redB[16][16];
  if (lane == 0) {
#pragma unroll
    for (int d = 0; d < 16; ++d) { redA[wv][d] = accA[d]; redB[wv][d] = accB[d]; }
  }
  __syncthreads();
  __shared__ float agA[16], agB[16], cA[16], cB[16], daF[16], dbF[16];
  __shared__ float vsh[CDEC], red[CDEC];
  if (t < 16) {
    float sA = 0.f, sB = 0.f;
#pragma unroll
    for (int w_ = 0; w_ < 16; ++w_) { sA += redA[w_][t]; sB += redB[w_][t]; }
    agA[t] = sA * qa.w;   // inv_deg scale
    agB[t] = sB * qb.w;
  }
  __syncthreads();
  if (t < 32) {
    int row = t >> 4, k = t & 15;
    const float* ag = row ? agB : agA;
    const float* self = out2 + ((size_t)(b * CN + (row ? ib : ia))) * 16;
    float s = 0.f;
    if (k < 8) {
#pragma unroll
      for (int d = 0; d < 16; ++d) s = fmaf(ag[d], w3[d * 8 + k], s);
    } else {
#pragma unroll
      for (int d = 0; d < 16; ++d) s = fmaf(self[d], b3[d * 8 + (k - 8)], s);
    }
    (row ? cB : cA)[k] = s;
  }
  __syncthreads();
  if (t < 32) {
    int row = t >> 4, k = t & 15;
    const float* c = row ? cB : cA;
    float nn = 0.f;
#pragma unroll
    for (int q = 0; q < 16; ++q) nn += c[q] * c[q];
    float inv = 1.f / fmaxf(sqrtf(nn), 1e-12f);
    float v = c[k] * inv;
    (row ? dbF : daF)[k] = (v >= 0.f) ? v : 0.1f * v;
  }
  __syncthreads();
  float ue = 0.f, ve = 0.f;
  if (t < CDEC) {
#pragma unroll
    for (int i = 0; i < 16; ++i) {
      ue = fmaf(daF[i], P1[i * CDEC + t], ue);
      ve = fmaf(dbF[i], P1[i * CDEC + t], ve);
    }
    vsh[t] = ve;
  }
  __syncthreads();
  if (t < CDEC) {
    float s = 0.f;
    for (int e2 = 0; e2 < CDEC; ++e2) s = fmaf(P2[t * CDEC + e2], vsh[e2], s);
    red[t] = s * ue;
  }
  __syncthreads();
  for (int off = 64; off; off >>= 1) {
    if (t < off) red[t] += red[t + off];
    __syncthreads();
  }
  if (t == 0) y[b] = red[0];
}

extern "C" void kernel_launch(void* const* d_in, const int* in_sizes, int n_in,
                              void* d_out, int out_size, void* d_ws, size_t ws_size,
                              hipStream_t stream) {
  const float* x       = (const float*)d_in[0];
  const int*   adj     = (const int*)d_in[1];
  const float* inv_deg = (const float*)d_in[2];
  const float* W       = (const float*)d_in[3];
  const float* a       = (const float*)d_in[4];
  const float* w1      = (const float*)d_in[5];
  const float* b1      = (const float*)d_in[6];
  const float* w2      = (const float*)d_in[7];
  const float* b2      = (const float*)d_in[8];
  const float* w3      = (const float*)d_in[9];
  const float* b3      = (const float*)d_in[10];
  const float* P1      = (const float*)d_in[11];
  const float* P2      = (const float*)d_in[12];
  float* y = (float*)d_out;

  char* base = (char*)d_ws;
  size_t off = 0;
  auto alloc = [&](size_t bytes) -> void* {
    void* r = base + off;
    off += (bytes + 255) & ~(size_t)255;
    return r;
  };
  float4* pk = (float4*)alloc(sizeof(float4) * CBN);
  float4* qk = (float4*)alloc(sizeof(float4) * CBN);
  unsigned long long* maskT = (unsigned long long*)alloc(sizeof(unsigned long long) * (size_t)CBN * NWRD);
  float* out1 = (float*)alloc(sizeof(float) * (size_t)CBN * 16);
  float* out2 = (float*)alloc(sizeof(float) * (size_t)CBN * 16);
  float* part = (float*)alloc(sizeof(float) * (size_t)JSP * CBN * 8);

  hipLaunchKernelGGL(prep_k, dim3(CBN / 256), dim3(256), 0, stream, x, inv_deg, W, a, pk, qk);
  hipLaunchKernelGGL(mask_k, dim3(CBN / 4), dim3(256), 0, stream, adj, pk, qk, maskT);

  // layer 1 (feat = x, DIN=8)
  hipLaunchKernelGGL(agg_k<8>, dim3(JSP, 4, CB), dim3(256), 0, stream, x, maskT, pk, qk, w1, part);
  hipLaunchKernelGGL(epi_k<8>, dim3(CBN / 256), dim3(256), 0, stream, part, x, qk, b1, out1);
  // layer 2 (feat = out1, DIN=16)
  hipLaunchKernelGGL(agg_k<16>, dim3(JSP, 4, CB), dim3(256), 0, stream, out1, maskT, pk, qk, w2, part);
  hipLaunchKernelGGL(epi_k<16>, dim3(CBN / 256), dim3(256), 0, stream, part, out1, qk, b2, out2);
  // layer 3 + decoder fused: only rows N-2, N-1 needed
  hipLaunchKernelGGL(fused3_k, dim3(CB), dim3(1024), 0, stream, out2, maskT, pk, qk,
                     w3, b3, P1, P2, y);
}

// Round 5
// 117.206 us; speedup vs baseline: 3.1264x; 1.0715x over previous
//
#include <hip/hip_runtime.h>
#include <math.h>

constexpr int CB   = 8;
constexpr int CN   = 2048;
constexpr int CD   = 8;
constexpr int CDEC = 128;
constexpr int CBN  = CB * CN;
constexpr int NWRD = CN / 64;   // 32 mask words per row
constexpr int JSP  = 32;        // j-split: part stays L2-resident
constexpr int JLEN = CN / JSP;  // 64

// lane-select: r = mask-bit[lane] ? p : 0  (mask is wave-uniform -> SGPR pair)
__device__ inline float msel(unsigned long long m, float p) {
  float r;
  asm("v_cndmask_b32 %0, 0, %1, %2" : "=v"(r) : "v"(p), "s"(m));
  return r;
}

// ---------------- prep: h = xW, f1/f2, exps ----------------
__global__ void prep_k(const float* __restrict__ x,
                       const float* __restrict__ W, const float* __restrict__ a,
                       float4* __restrict__ pk, float4* __restrict__ qk) {
  int t = blockIdx.x * blockDim.x + threadIdx.x;
  if (t >= CBN) return;
  const float* xr = x + (size_t)t * CD;
  float h[CD];
#pragma unroll
  for (int d = 0; d < CD; ++d) {
    float s = 0.f;
#pragma unroll
    for (int k = 0; k < CD; ++k) s = fmaf(xr[k], W[k * CD + d], s);
    h[d] = s;
  }
  float s1 = 0.f, s2 = 0.f;
#pragma unroll
  for (int d = 0; d < CD; ++d) { s1 = fmaf(h[d], a[d], s1); s2 = fmaf(h[d], a[CD + d], s2); }
  pk[t] = make_float4(s1, expf(s1), expf(0.2f * s1), 0.f);
  qk[t] = make_float4(s2, expf(s2), expf(0.2f * s2), 0.f);
}

// -- mask build (transposed) + softmax row sums + inv_deg from popcount -----
__global__ void mask_k(const int* __restrict__ adj, float4* __restrict__ pk,
                       const float4* __restrict__ qk, unsigned long long* __restrict__ maskT) {
  int gw   = (blockIdx.x * blockDim.x + threadIdx.x) >> 6;  // row index (b*CN+j)
  int lane = threadIdx.x & 63;
  if (gw >= CBN) return;
  int b = gw / CN, j = gw - b * CN;
  const int* arow = adj + (size_t)gw * CN;
  float4 pj = pk[gw];
  float f1j = pj.x;
  const float4* qb = qk + (size_t)b * CN;
  float A = 0.f, C = 0.f;
  int deg = 0;
  for (int k = 0; k < NWRD; ++k) {
    int i = k * 64 + lane;
    bool bit = arow[i] > 0;
    unsigned long long m = __ballot(bit);
    if (lane == 0) {
      maskT[((size_t)(b * NWRD + k)) * CN + j] = m;  // [b][word][j]
      deg += __popcll(m);
    }
    float4 q = qb[i];
    bool cond = (f1j + q.x) >= 0.f;
    A += (bit && cond) ? q.y : 0.f;
    C += (bit && !cond) ? q.z : 0.f;
  }
#pragma unroll
  for (int off = 32; off; off >>= 1) { A += __shfl_down(A, off); C += __shfl_down(C, off); }
  if (lane == 0) {
    float s = pj.y * A + pj.z * C;  // E1*sum_pos(E2) + F1*sum_neg(F2)
    float ga = (s > 0.f) ? pj.y / s : 0.f;
    float gb = (s > 0.f) ? pj.z / s : 0.f;
    float dv = 1.f / (float)(deg + 1);   // diag(inv_deg) for node j
    pk[gw] = make_float4(f1j, ga, gb, dv);
  }
}

// --- aggregation: part[js][b,i][o] = (sum_{j in chunk} attn[j,i]*feat[j,:]) @ wmat
// attn[j,i] = max(g1j*E2i, g2j*F2i) masked   (exp∘leaky = max of branch exps)
template <int DIN>
__global__ __launch_bounds__(256) void agg_k(const float* __restrict__ feat,
                      const unsigned long long* __restrict__ maskT,
                      const float4* __restrict__ pk, const float4* __restrict__ qk,
                      const float* __restrict__ wmat, float* __restrict__ part) {
  const int js = blockIdx.x, ic = blockIdx.y, b = blockIdx.z;
  const int t = threadIdx.x;
  const int w = __builtin_amdgcn_readfirstlane(t >> 6);
  const int i1 = ic * 512 + t;   // slot 0
  const int i2 = i1 + 256;       // slot 1
  const int gi1 = b * CN + i1, gi2 = b * CN + i2;
  float4 q1 = qk[gi1], q2 = qk[gi2];
  const unsigned long long* mc1 = maskT + ((size_t)(b * NWRD + ic * 8 + w)) * CN + js * JLEN;
  const unsigned long long* mc2 = maskT + ((size_t)(b * NWRD + ic * 8 + 4 + w)) * CN + js * JLEN;
  const float4* pb = pk + (size_t)b * CN + js * JLEN;
  const float* fb  = feat + ((size_t)b * CN + js * JLEN) * DIN;
  float acc1[DIN], acc2[DIN];
#pragma unroll
  for (int d = 0; d < DIN; ++d) { acc1[d] = 0.f; acc2[d] = 0.f; }
#pragma unroll 4
  for (int jj = 0; jj < JLEN; ++jj) {
    unsigned long long m1 = mc1[jj];            // wave-uniform, contiguous stream
    unsigned long long m2 = mc2[jj];
    float4 pj = pb[jj];                         // {f1j, g1j, g2j, dv} uniform
    const float* fr = fb + jj * DIN;            // uniform
    float wA = msel(m1, fmaxf(pj.y * q1.y, pj.z * q1.z));
    float wB = msel(m2, fmaxf(pj.y * q2.y, pj.z * q2.z));
#pragma unroll
    for (int d = 0; d < DIN; ++d) {
      acc1[d] = fmaf(wA, fr[d], acc1[d]);
      acc2[d] = fmaf(wB, fr[d], acc2[d]);
    }
  }
  // fold the @wmat (DIN -> 8) into the partial store
  float o1[8], o2[8];
#pragma unroll
  for (int o = 0; o < 8; ++o) {
    float s1 = 0.f, s2 = 0.f;
#pragma unroll
    for (int d = 0; d < DIN; ++d) {
      s1 = fmaf(acc1[d], wmat[d * 8 + o], s1);
      s2 = fmaf(acc2[d], wmat[d * 8 + o], s2);
    }
    o1[o] = s1;
    o2[o] = s2;
  }
  float4* p1 = (float4*)(part + ((size_t)js * CBN + gi1) * 8);
  float4* p2 = (float4*)(part + ((size_t)js * CBN + gi2) * 8);
  p1[0] = make_float4(o1[0], o1[1], o1[2], o1[3]);
  p1[1] = make_float4(o1[4], o1[5], o1[6], o1[7]);
  p2[0] = make_float4(o2[0], o2[1], o2[2], o2[3]);
  p2[1] = make_float4(o2[4], o2[5], o2[6], o2[7]);
}

// ---- epilogue: sum partials, inv_deg scale, self@b, concat, norm, leaky ----
template <int DIN>
__global__ void epi_k(const float* __restrict__ part, const float* __restrict__ feat,
                      const float4* __restrict__ pk, const float* __restrict__ bmat,
                      float* __restrict__ out) {
  int t = blockIdx.x * blockDim.x + threadIdx.x;
  if (t >= CBN) return;
  float4 a0 = make_float4(0.f, 0.f, 0.f, 0.f), a1 = a0;
  for (int p_ = 0; p_ < JSP; ++p_) {
    const float4* pr = (const float4*)(part + ((size_t)p_ * CBN + t) * 8);
    float4 r0 = pr[0], r1 = pr[1];
    a0.x += r0.x; a0.y += r0.y; a0.z += r0.z; a0.w += r0.w;
    a1.x += r1.x; a1.y += r1.y; a1.z += r1.z; a1.w += r1.w;
  }
  float ag[8] = {a0.x, a0.y, a0.z, a0.w, a1.x, a1.y, a1.z, a1.w};
  float di = pk[t].w;
  const float* fr = feat + (size_t)t * DIN;
  float c[16];
#pragma unroll
  for (int o = 0; o < 8; ++o) {
    float s2 = 0.f;
#pragma unroll
    for (int d = 0; d < DIN; ++d) s2 = fmaf(fr[d], bmat[d * 8 + o], s2);
    c[o] = ag[o] * di;
    c[8 + o] = s2;
  }
  float nn = 0.f;
#pragma unroll
  for (int k = 0; k < 16; ++k) nn += c[k] * c[k];
  float inv = 1.f / fmaxf(sqrtf(nn), 1e-12f);
  float4* orow = (float4*)(out + (size_t)t * 16);
#pragma unroll
  for (int q = 0; q < 4; ++q) {
    float v0 = c[q*4+0]*inv, v1 = c[q*4+1]*inv, v2 = c[q*4+2]*inv, v3 = c[q*4+3]*inv;
    orow[q] = make_float4(v0 >= 0.f ? v0 : 0.1f*v0, v1 >= 0.f ? v1 : 0.1f*v1,
                          v2 >= 0.f ? v2 : 0.1f*v2, v3 >= 0.f ? v3 : 0.1f*v3);
  }
}

// ---- fused layer 3 + decoder: only rows i = N-2, N-1 are ever consumed ----
__global__ __launch_bounds__(1024) void fused3_k(
    const float* __restrict__ out2, const unsigned long long* __restrict__ maskT,
    const float4* __restrict__ pk, const float4* __restrict__ qk,
    const float* __restrict__ w3, const float* __restrict__ b3,
    const float* __restrict__ P1, const float* __restrict__ P2,
    float* __restrict__ y) {
  const int b = blockIdx.x;
  const int t = threadIdx.x;
  const int lane = t & 63, wv = t >> 6;  // 16 waves
  const int ia = CN - 2, ib = CN - 1;
  float4 qa = qk[b * CN + ia], qb = qk[b * CN + ib];
  float dva = pk[b * CN + ia].w, dvb = pk[b * CN + ib].w;
  float accA[16], accB[16];
#pragma unroll
  for (int d = 0; d < 16; ++d) { accA[d] = 0.f; accB[d] = 0.f; }
  const unsigned long long* mrow = maskT + ((size_t)(b * NWRD + (NWRD - 1))) * CN;
  for (int j = t; j < CN; j += 1024) {
    unsigned long long m = mrow[j];
    float4 pj = pk[b * CN + j];
    const float4* fr = (const float4*)(out2 + ((size_t)(b * CN + j)) * 16);
    float wA = fmaxf(pj.y * qa.y, pj.z * qa.z);
    wA = ((m >> 62) & 1ull) ? wA : 0.f;     // bit for i = N-2
    float wB = fmaxf(pj.y * qb.y, pj.z * qb.z);
    wB = (m >> 63) ? wB : 0.f;              // bit for i = N-1
    float4 f0 = fr[0], f1 = fr[1], f2 = fr[2], f3 = fr[3];
    float ff[16] = {f0.x,f0.y,f0.z,f0.w, f1.x,f1.y,f1.z,f1.w,
                    f2.x,f2.y,f2.z,f2.w, f3.x,f3.y,f3.z,f3.w};
#pragma unroll
    for (int d = 0; d < 16; ++d) {
      accA[d] = fmaf(wA, ff[d], accA[d]);
      accB[d] = fmaf(wB, ff[d], accB[d]);
    }
  }
#pragma unroll
  for (int d = 0; d < 16; ++d) {
#pragma unroll
    for (int off = 32; off; off >>= 1) {
      accA[d] += __shfl_down(accA[d], off);
      accB[d] += __shfl_down(accB[d], off);
    }
  }
  __shared__ float redA[16][16], redB[16][16];
  if (lane == 0) {
#pragma unroll
    for (int d = 0; d < 16; ++d) { redA[wv][d] = accA[d]; redB[wv][d] = accB[d]; }
  }
  __syncthreads();
  __shared__ float agA[16], agB[16], cA[16], cB[16], daF[16], dbF[16];
  __shared__ float vsh[CDEC], red[CDEC];
  if (t < 16) {
    float sA = 0.f, sB = 0.f;
#pragma unroll
    for (int w_ = 0; w_ < 16; ++w_) { sA += redA[w_][t]; sB += redB[w_][t]; }
    agA[t] = sA * dva;   // inv_deg scale
    agB[t] = sB * dvb;
  }
  __syncthreads();
  if (t < 32) {
    int row = t >> 4, k = t & 15;
    const float* ag = row ? agB : agA;
    const float* self = out2 + ((size_t)(b * CN + (row ? ib : ia))) * 16;
    float s = 0.f;
    if (k < 8) {
#pragma unroll
      for (int d = 0; d < 16; ++d) s = fmaf(ag[d], w3[d * 8 + k], s);
    } else {
#pragma unroll
      for (int d = 0; d < 16; ++d) s = fmaf(self[d], b3[d * 8 + (k - 8)], s);
    }
    (row ? cB : cA)[k] = s;
  }
  __syncthreads();
  if (t < 32) {
    int row = t >> 4, k = t & 15;
    const float* c = row ? cB : cA;
    float nn = 0.f;
#pragma unroll
    for (int q = 0; q < 16; ++q) nn += c[q] * c[q];
    float inv = 1.f / fmaxf(sqrtf(nn), 1e-12f);
    float v = c[k] * inv;
    (row ? dbF : daF)[k] = (v >= 0.f) ? v : 0.1f * v;
  }
  __syncthreads();
  float ue = 0.f, ve = 0.f;
  if (t < CDEC) {
#pragma unroll
    for (int i = 0; i < 16; ++i) {
      ue = fmaf(daF[i], P1[i * CDEC + t], ue);
      ve = fmaf(dbF[i], P1[i * CDEC + t], ve);
    }
    vsh[t] = ve;
  }
  __syncthreads();
  if (t < CDEC) {
    float s = 0.f;
    for (int e2 = 0; e2 < CDEC; ++e2) s = fmaf(P2[t * CDEC + e2], vsh[e2], s);
    red[t] = s * ue;
  }
  __syncthreads();
  for (int off = 64; off; off >>= 1) {
    if (t < off) red[t] += red[t + off];
    __syncthreads();
  }
  if (t == 0) y[b] = red[0];
}

extern "C" void kernel_launch(void* const* d_in, const int* in_sizes, int n_in,
                              void* d_out, int out_size, void* d_ws, size_t ws_size,
                              hipStream_t stream) {
  const float* x       = (const float*)d_in[0];
  const int*   adj     = (const int*)d_in[1];
  const float* W       = (const float*)d_in[3];
  const float* a       = (const float*)d_in[4];
  const float* w1      = (const float*)d_in[5];
  const float* b1      = (const float*)d_in[6];
  const float* w2      = (const float*)d_in[7];
  const float* b2      = (const float*)d_in[8];
  const float* w3      = (const float*)d_in[9];
  const float* b3      = (const float*)d_in[10];
  const float* P1      = (const float*)d_in[11];
  const float* P2      = (const float*)d_in[12];
  float* y = (float*)d_out;

  char* base = (char*)d_ws;
  size_t off = 0;
  auto alloc = [&](size_t bytes) -> void* {
    void* r = base + off;
    off += (bytes + 255) & ~(size_t)255;
    return r;
  };
  float4* pk = (float4*)alloc(sizeof(float4) * CBN);
  float4* qk = (float4*)alloc(sizeof(float4) * CBN);
  unsigned long long* maskT = (unsigned long long*)alloc(sizeof(unsigned long long) * (size_t)CBN * NWRD);
  float* out1 = (float*)alloc(sizeof(float) * (size_t)CBN * 16);
  float* out2 = (float*)alloc(sizeof(float) * (size_t)CBN * 16);
  float* part = (float*)alloc(sizeof(float) * (size_t)JSP * CBN * 8);

  hipLaunchKernelGGL(prep_k, dim3(CBN / 256), dim3(256), 0, stream, x, W, a, pk, qk);
  hipLaunchKernelGGL(mask_k, dim3(CBN / 4), dim3(256), 0, stream, adj, pk, qk, maskT);

  // layer 1 (feat = x, DIN=8)
  hipLaunchKernelGGL(agg_k<8>, dim3(JSP, 4, CB), dim3(256), 0, stream, x, maskT, pk, qk, w1, part);
  hipLaunchKernelGGL(epi_k<8>, dim3(CBN / 256), dim3(256), 0, stream, part, x, pk, b1, out1);
  // layer 2 (feat = out1, DIN=16)
  hipLaunchKernelGGL(agg_k<16>, dim3(JSP, 4, CB), dim3(256), 0, stream, out1, maskT, pk, qk, w2, part);
  hipLaunchKernelGGL(epi_k<16>, dim3(CBN / 256), dim3(256), 0, stream, part, out1, pk, b2, out2);
  // layer 3 + decoder fused: only rows N-2, N-1 needed
  hipLaunchKernelGGL(fused3_k, dim3(CB), dim3(1024), 0, stream, out2, maskT, pk, qk,
                     w3, b3, P1, P2, y);
}